// Round 15
// baseline (152.949 us; speedup 1.0000x reference)
//
#include <hip/hip_runtime.h>

// mean(|box5(x) - box5(y)|), box5 = 5x5 uniform, pad=4.
// box(x)-box(y) = box(x-y), separable.
//
// Round-15: WIDTH-SPLIT PAIR RELAY. Measured law (r8/r13/r14): aggregate
// service rate ~= in-flight bytes / ~14us, saturating ~4 TB/s; duration =
// logical bytes / rate. So: tall strips (R=17, amp 1.235, logical 158 MB)
// AND high wave count via 2 waves per strip (left/right 256-col halves,
// 4 cols/lane) AND 8-row chunks (16 KB outstanding/wave; same stage-reg
// count as r8's proven config). In-flight ~63 MB ~= r13's best.
// Seam: right wave's lane-0 halo (cols 252..255 vsum) = left wave's
// lane-63 v[0..3], relayed via 16 B/row LDS snapshots; ONE barrier per
// chunk (3/strip), double-buffered snaps; right wave consumes chunk c
// after the barrier while its chunk-c loads completed during the wait.

#define IMG_W 512
#define IMG_H 512
#define OUT_W 516
#define OUT_H 516
#define R     17                 // output rows per strip (odd: 16 phases)
#define SPI   31                 // ceil(516/17) row-groups per image
#define NT    256                // 4 waves = 2 pairs per block
#define NGRP  (64 * SPI)         // 1984 row-group strips
#define NBLK  (NGRP / 2)         // 992 blocks (124/XCD, bijective)
#define NPART 64
#define NROWS 21                 // input rows per strip (R + 4)

typedef float v4f __attribute__((ext_vector_type(4)));

__global__ __launch_bounds__(NT, 2) void box_loss_kernel(
    const float* __restrict__ x, const float* __restrict__ y,
    float* __restrict__ partial)
{
    const int t    = threadIdx.x;
    const int lane = t & 63;
    const int wid  = t >> 6;
    const int pair = wid >> 1;          // 0..1: two strip-pairs per block
    const int h    = wid & 1;           // 0=left half, 1=right half

    // bijective XCD swizzle: 992 blocks -> 124 contiguous per XCD
    const int bid  = blockIdx.x;
    const int swz  = (bid & 7) * (NBLK / 8) + (bid >> 3);

    const int g  = swz * 2 + pair;      // row-group strip id, 0..1983
    const int b  = g / SPI;             // batch image
    const int s  = g - b * SPI;         // row-group in image
    const int i0 = s * R;               // first output row
    const int c0 = h * 256 + 4 * lane;  // this lane's 4 columns

    const float* xb = x + (size_t)b * (IMG_W * IMG_H) + c0;
    const float* yb = y + (size_t)b * (IMG_W * IMG_H) + c0;

    // seam relay: wave0 lane63's v[0..3] per row, double-buffered
    __shared__ float snap[2][2][8][4];  // [pair][buf][row-in-chunk][j]

    // stage registers: 8 rows x (x,y), 16 v4f (r8-proven budget)
    v4f sx[8], sy[8];

    // 5-row d-history ring + vertical rolling sums (4 cols/lane)
    float ring[5][4];
    float v[4];
    #pragma unroll
    for (int j = 0; j < 4; ++j) { v[j] = 0.f; ring[4][j] = 0.f; }

    float acc = 0.f;

// stage chunk rows [base, base+nr): x rows then y rows, fence-pinned
#define STAGE(base, nr)                                                   \
    __builtin_amdgcn_sched_barrier(0);                                    \
    _Pragma("unroll")                                                     \
    for (int q = 0; q < (nr); ++q) {                                      \
        const int rc = min(max(i0 - 4 + (base) + q, 0), IMG_H - 1);       \
        sx[q] = *(const v4f*)(xb + (size_t)rc * IMG_W);                   \
    }                                                                     \
    _Pragma("unroll")                                                     \
    for (int q = 0; q < (nr); ++q) {                                      \
        const int rc = min(max(i0 - 4 + (base) + q, 0), IMG_H - 1);       \
        sy[q] = *(const v4f*)(yb + (size_t)rc * IMG_W);                   \
    }                                                                     \
    __builtin_amdgcn_sched_barrier(0);

// consume chunk rows [base, base+nr); LEFT writes snaps, RIGHT reads them
#define CONSUME(base, nr, buf, isLeft)                                    \
    _Pragma("unroll")                                                     \
    for (int q = 0; q < (nr); ++q) {                                      \
        const int k = (base) + q;           /* 0..20, compile-time */     \
        const int r = i0 - 4 + k;                                         \
        const float m = (r >= 0 && r < IMG_H) ? 1.f : 0.f;                \
        float d[4];                                                       \
        d[0] = (sx[q].x - sy[q].x) * m; d[1] = (sx[q].y - sy[q].y) * m;   \
        d[2] = (sx[q].z - sy[q].z) * m; d[3] = (sx[q].w - sy[q].w) * m;   \
        if (k < 4) {                                                      \
            _Pragma("unroll")                                             \
            for (int j = 0; j < 4; ++j) { ring[k][j] = d[j]; v[j] += d[j]; } \
        } else {                                                          \
            const int slot = k % 5;                                       \
            _Pragma("unroll")                                             \
            for (int j = 0; j < 4; ++j) {                                 \
                v[j] += d[j] - ring[slot][j]; ring[slot][j] = d[j];       \
            }                                                             \
            float h0 = __shfl_up(v[0], 1, 64);                            \
            float h1 = __shfl_up(v[1], 1, 64);                            \
            float h2 = __shfl_up(v[2], 1, 64);                            \
            float h3 = __shfl_up(v[3], 1, 64);                            \
            if (isLeft) {                                                 \
                if (lane == 0) { h0 = 0.f; h1 = 0.f; h2 = 0.f; h3 = 0.f; }\
                if (lane == 63) {                                         \
                    snap[pair][buf][q][0] = v[0];                         \
                    snap[pair][buf][q][1] = v[1];                         \
                    snap[pair][buf][q][2] = v[2];                         \
                    snap[pair][buf][q][3] = v[3];                         \
                }                                                         \
            } else {                                                      \
                if (lane == 0) {                                          \
                    h0 = snap[pair][buf][q][0];                           \
                    h1 = snap[pair][buf][q][1];                           \
                    h2 = snap[pair][buf][q][2];                           \
                    h3 = snap[pair][buf][q][3];                           \
                }                                                         \
            }                                                             \
            const float s0 = h0 + h1 + h2 + h3 + v[0];                    \
            const float s1 = s0 - h0 + v[1];                              \
            const float s2 = s1 - h1 + v[2];                              \
            const float s3 = s2 - h2 + v[3];                              \
            const int i = i0 + (k - 4);                                   \
            const float rowmask = (i < OUT_H) ? 1.f : 0.f;                \
            acc += rowmask * (fabsf(s0) + fabsf(s1)                       \
                            + fabsf(s2) + fabsf(s3));                     \
            if (!(isLeft) && lane == 63) {                                \
                const float e0 = v[0] + v[1] + v[2] + v[3];               \
                const float e1 = v[1] + v[2] + v[3];                      \
                const float e2 = v[2] + v[3];                             \
                const float e3 = v[3];                                    \
                acc += rowmask * (fabsf(e0) + fabsf(e1)                   \
                                + fabsf(e2) + fabsf(e3));                 \
            }                                                             \
        }                                                                 \
    }

// one pipeline step: stage, left consumes+snaps, barrier, right consumes
#define CHUNK(base, nr, cidx)                                             \
    STAGE(base, nr)                                                       \
    if (h == 0) { CONSUME(base, nr, (cidx) & 1, true) }                   \
    __syncthreads();                                                      \
    if (h == 1) { CONSUME(base, nr, (cidx) & 1, false) }

    // 21 input rows in chunks {8,8,5}; 3 barriers per strip
    CHUNK(0, 8, 0)
    CHUNK(8, 8, 1)
    CHUNK(16, 5, 2)

    // wave reduction, then one atomic per wave spread across 64 slots
    #pragma unroll
    for (int off = 32; off > 0; off >>= 1)
        acc += __shfl_down(acc, off, 64);
    if (lane == 0)
        atomicAdd(partial + ((g * 2 + h) & (NPART - 1)), acc);
}

__global__ void finalize_kernel(const float* __restrict__ partial,
                                float* __restrict__ out)
{
    float s = 0.f;
    #pragma unroll
    for (int k = 0; k < NPART; ++k) s += partial[k];
    // each output scaled by 1/25 (uniform kernel), mean over 64*516*516
    out[0] = s * (1.0f / (25.0f * 64.0f * 516.0f * 516.0f));
}

extern "C" void kernel_launch(void* const* d_in, const int* in_sizes, int n_in,
                              void* d_out, int out_size, void* d_ws, size_t ws_size,
                              hipStream_t stream) {
    const float* x = (const float*)d_in[0];
    const float* y = (const float*)d_in[1];
    float* out = (float*)d_out;
    float* ws  = (float*)d_ws;

    hipMemsetAsync(ws, 0, NPART * sizeof(float), stream);

    dim3 grid(NBLK);   // 992 blocks x 256 threads = 3968 waves
    box_loss_kernel<<<grid, NT, 0, stream>>>(x, y, ws);
    finalize_kernel<<<1, 1, 0, stream>>>(ws, out);
}